// Round 17
// baseline (204.197 us; speedup 1.0000x reference)
//
#include <hip/hip_runtime.h>
#include <hip/hip_bf16.h>

#define NN 50000
#define EE 600000
#define FF 128
#define HH 128
#define CC 10
#define GG 64
#define SB 256
#define NBSCAN ((NN + SB - 1) / SB)   // 196
#define FILLB ((EE + 255) / 256)      // 2344
#define GEMMB ((NN + 63) / 64)        // 782

typedef unsigned int uint32;
typedef unsigned short ushort16;
typedef __attribute__((ext_vector_type(8))) short short8;
typedef __attribute__((ext_vector_type(4))) float f32x4;

__device__ __forceinline__ ushort16 f2bf(float f) {
    __hip_bfloat16 b = __float2bfloat16(f);
    return *reinterpret_cast<ushort16*>(&b);
}
__device__ __forceinline__ uint32 pack2bf(float a, float b) {
    return (uint32)f2bf(a) | ((uint32)f2bf(b) << 16);
}
// int8 quantize with scale 16, clamp +-127
__device__ __forceinline__ int q8(float f) {
    return __float2int_rn(fminf(fmaxf(f * 16.f, -127.f), 127.f)) & 255;
}
// decode byte j (0..3) of u as signed int8 -> float
#define B2F(w, j) ((float)((int)((w) << (24 - 8 * (j))) >> 24))

// ---------------- degree count ----------------
__global__ void count_deg(const int* __restrict__ dst, int* __restrict__ deg) {
    int e = blockIdx.x * blockDim.x + threadIdx.x;
    if (e < EE) atomicAdd(&deg[dst[e]], 1);
}

// ---------------- scan stage 1 (+ dinv fused) ----------------
__global__ __launch_bounds__(SB) void scan_block(const int* __restrict__ deg,
                                                 int* __restrict__ row_ptr,
                                                 int* __restrict__ bsum,
                                                 float* __restrict__ dinv) {
    __shared__ int sm[SB];
    int t = threadIdx.x;
    int i = blockIdx.x * SB + t;
    int v = (i < NN) ? deg[i] : 0;
    if (i < NN) dinv[i] = rsqrtf((float)(v + 1));
    sm[t] = v;
    __syncthreads();
    for (int off = 1; off < SB; off <<= 1) {
        int add = (t >= off) ? sm[t - off] : 0;
        __syncthreads();
        sm[t] += add;
        __syncthreads();
    }
    if (i < NN) row_ptr[i] = sm[t] - v;
    if (t == SB - 1) bsum[blockIdx.x] = sm[t];
}

__global__ void scan_bsum(int* __restrict__ bsum, int nb) {
    __shared__ int sm[256];
    int t = threadIdx.x;
    int v = (t < nb) ? bsum[t] : 0;
    sm[t] = v;
    __syncthreads();
    for (int off = 1; off < 256; off <<= 1) {
        int add = (t >= off) ? sm[t - off] : 0;
        __syncthreads();
        sm[t] += add;
        __syncthreads();
    }
    if (t < nb) bsum[t] = sm[t] - v;
}

// ---------------- scan stage 3 + cursor copy + W transpose (W1,W2) ----------------
__global__ __launch_bounds__(SB) void scan_add_tw(int* __restrict__ row_ptr,
                                                  int* __restrict__ cursor,
                                                  const int* __restrict__ bsum,
                                                  const float* __restrict__ W1,
                                                  const float* __restrict__ W2,
                                                  ushort16* __restrict__ T1,
                                                  ushort16* __restrict__ T2) {
    int b = blockIdx.x;
    if (b < NBSCAN) {
        int i = b * SB + threadIdx.x;
        if (i < NN) {
            int v = row_ptr[i] + bsum[b];
            row_ptr[i] = v;
            cursor[i] = v;            // fill bumps this copy directly
        }
        if (i == 0) row_ptr[NN] = EE;
    } else {
        int bi = b - NBSCAN;                 // 0..31
        int wi = bi >> 4;
        const float* W = (wi == 0) ? W1 : W2;
        ushort16* T = (wi == 0) ? T1 : T2;
        int base = (bi & 15) * 256 + threadIdx.x;
#pragma unroll
        for (int i = 0; i < 4; i++) {
            int idx = base + i * 4096;       // 0..16383
            int col = idx & 127;
            int k = idx >> 7;
            T[col * 128 + k] = f2bf(W[k * 128 + col]);
        }
    }
}

// ---------------- fused: gemm1 (z1 = q8(x@W1)) || CSR fill (int2 entries) ------------
__global__ __launch_bounds__(256) void fill_gemm(const float* __restrict__ A,
                                                 const ushort16* __restrict__ Wt,
                                                 uint32* __restrict__ zout,
                                                 const int* __restrict__ src,
                                                 const int* __restrict__ dst,
                                                 int* __restrict__ cursor,
                                                 const float* __restrict__ dinv,
                                                 int2* __restrict__ csr_en) {
    __shared__ char lds[34816];
    int t = threadIdx.x;
    if (blockIdx.x >= GEMMB) {
        // ---- CSR fill part (r15 semantics: (src byte offset, dinv[src]/16)) ----
        int e = (blockIdx.x - GEMMB) * 256 + t;
        if (e < EE) {
            int s = src[e], d = dst[e];
            int pos = atomicAdd(&cursor[d], 1);
            csr_en[pos] = make_int2(s * 128, __float_as_int(dinv[s] * 0.0625f));
        }
        return;
    }
    // ---- GEMM part ----
    int w = t >> 6, l = t & 63;
    int lrow = l & 15, g = l >> 4;
    int rowBase = blockIdx.x * 64;
    int arow = rowBase + w * 16 + lrow;
    short8 afr[4];
    const char* Ab = (const char*)A;
    bool inb = arow < NN;
#pragma unroll
    for (int s = 0; s < 4; s++) {
        if (inb) {
            float4 f0 = *(const float4*)(Ab + (size_t)arow * 512 + s * 128 + g * 32);
            float4 f1 = *(const float4*)(Ab + (size_t)arow * 512 + s * 128 + g * 32 + 16);
            union { short8 s8; uint32 u[4]; } cv;
            cv.u[0] = pack2bf(f0.x, f0.y);
            cv.u[1] = pack2bf(f0.z, f0.w);
            cv.u[2] = pack2bf(f1.x, f1.y);
            cv.u[3] = pack2bf(f1.z, f1.w);
            afr[s] = cv.s8;
        } else {
            short8 z = {0, 0, 0, 0, 0, 0, 0, 0};
            afr[s] = z;
        }
    }
    const char* Wb = (const char*)Wt;
#pragma unroll
    for (int i = 0; i < 8; i++) {
        int idx = t + i * 256;
        int col = idx >> 4, c16 = idx & 15;
        *(uint4*)(lds + col * 272 + c16 * 16) = *(const uint4*)(Wb + col * 256 + c16 * 16);
    }
    __syncthreads();
    f32x4 acc[8];
#pragma unroll
    for (int c = 0; c < 8; c++) { f32x4 z = {0.f, 0.f, 0.f, 0.f}; acc[c] = z; }
#pragma unroll
    for (int s = 0; s < 4; s++) {
#pragma unroll
        for (int c = 0; c < 8; c++) {
            short8 b = *(const short8*)(lds + (c * 16 + lrow) * 272 + s * 64 + g * 16);
            acc[c] = __builtin_amdgcn_mfma_f32_16x16x32_bf16(afr[s], b, acc[c], 0, 0, 0);
        }
    }
    __syncthreads();
    char* myl = lds + w * 8448;
#pragma unroll
    for (int c = 0; c < 8; c++) {
#pragma unroll
        for (int j = 0; j < 4; j++) {
            *(float*)(myl + (g * 4 + j) * 528 + (c * 16 + lrow) * 4) = acc[c][j];
        }
    }
    __syncthreads();
#pragma unroll
    for (int j = 0; j < 8; j++) {
        int rl = (l >> 5) + 2 * j;
        int ch = l & 31;
        float4 v = *(const float4*)(myl + rl * 528 + ch * 16);
        int grow = rowBase + w * 16 + rl;
        if (grow < NN) {
            uint32 u = q8(v.x) | (q8(v.y) << 8) | (q8(v.z) << 16) | (q8(v.w) << 24);
            zout[(size_t)grow * 32 + ch] = u;
        }
    }
}

// ---------------- gemm: bf16 h rows @ W -> int8 z rows ----------------
__global__ __launch_bounds__(256) void gemm_h(const ushort16* __restrict__ A,
                                              const ushort16* __restrict__ Wt,
                                              uint32* __restrict__ zout) {
    __shared__ char lds[34816];
    int t = threadIdx.x;
    int w = t >> 6, l = t & 63;
    int lrow = l & 15, g = l >> 4;
    int rowBase = blockIdx.x * 64;
    int arow = rowBase + w * 16 + lrow;
    short8 afr[4];
    const char* Ab = (const char*)A;
    bool inb = arow < NN;
#pragma unroll
    for (int s = 0; s < 4; s++) {
        if (inb) {
            afr[s] = *(const short8*)(Ab + (size_t)arow * 256 + s * 64 + g * 16);
        } else {
            short8 z = {0, 0, 0, 0, 0, 0, 0, 0};
            afr[s] = z;
        }
    }
    const char* Wb = (const char*)Wt;
#pragma unroll
    for (int i = 0; i < 8; i++) {
        int idx = t + i * 256;
        int col = idx >> 4, c16 = idx & 15;
        *(uint4*)(lds + col * 272 + c16 * 16) = *(const uint4*)(Wb + col * 256 + c16 * 16);
    }
    __syncthreads();
    f32x4 acc[8];
#pragma unroll
    for (int c = 0; c < 8; c++) { f32x4 z = {0.f, 0.f, 0.f, 0.f}; acc[c] = z; }
#pragma unroll
    for (int s = 0; s < 4; s++) {
#pragma unroll
        for (int c = 0; c < 8; c++) {
            short8 b = *(const short8*)(lds + (c * 16 + lrow) * 272 + s * 64 + g * 16);
            acc[c] = __builtin_amdgcn_mfma_f32_16x16x32_bf16(afr[s], b, acc[c], 0, 0, 0);
        }
    }
    __syncthreads();
    char* myl = lds + w * 8448;
#pragma unroll
    for (int c = 0; c < 8; c++) {
#pragma unroll
        for (int j = 0; j < 4; j++) {
            *(float*)(myl + (g * 4 + j) * 528 + (c * 16 + lrow) * 4) = acc[c][j];
        }
    }
    __syncthreads();
#pragma unroll
    for (int j = 0; j < 8; j++) {
        int rl = (l >> 5) + 2 * j;
        int ch = l & 31;
        float4 v = *(const float4*)(myl + rl * 528 + ch * 16);
        int grow = rowBase + w * 16 + rl;
        if (grow < NN) {
            uint32 u = q8(v.x) | (q8(v.y) << 8) | (q8(v.z) << 16) | (q8(v.w) << 24);
            zout[(size_t)grow * 32 + ch] = u;
        }
    }
}

// decode-accumulate 4 int8 lanes with per-edge weight (dinv[src]/16)
#define AGG_FMA4(c, v)                                             \
    {                                                              \
        float nm = __int_as_float((c).y);                          \
        a0 += nm * B2F(v, 0);                                      \
        a1 += nm * B2F(v, 1);                                      \
        a2 += nm * B2F(v, 2);                                      \
        a3 += nm * B2F(v, 3);                                      \
    }

// ---------------- aggregation: 32-lane group per node, 4-deep pipeline ----------------
// MODE 0: relu -> bf16 row (for gemm_h). MODE 1: relu -> int8 row (h2 for pool_gather).
template <int MODE>
__global__ __launch_bounds__(256) void aggregate(const uint32* __restrict__ z8,
                                                 const int* __restrict__ row_ptr,
                                                 const int2* __restrict__ csr_en,
                                                 const float* __restrict__ dinv,
                                                 const float* __restrict__ bias,
                                                 void* __restrict__ outv) {
    int grp = threadIdx.x >> 5;          // 0..7
    int ll  = threadIdx.x & 31;
    int n = blockIdx.x * 8 + grp;        // NN % 8 == 0
    const char* base = (const char*)z8;
    int boff = ll << 2;
    uint32 uself = *(const uint32*)(base + (size_t)n * 128 + boff);  // issue early
    float dn = dinv[n];
    float a0 = 0.f, a1 = 0.f, a2 = 0.f, a3 = 0.f;
    int s = row_ptr[n], e = row_ptr[n + 1];
    int k = s;
    if (k + 4 <= e) {
        int2 c0 = csr_en[k], c1 = csr_en[k + 1], c2 = csr_en[k + 2], c3 = csr_en[k + 3];
        uint32 v0 = *(const uint32*)(base + (size_t)(uint32)c0.x + boff);
        uint32 v1 = *(const uint32*)(base + (size_t)(uint32)c1.x + boff);
        uint32 v2 = *(const uint32*)(base + (size_t)(uint32)c2.x + boff);
        uint32 v3 = *(const uint32*)(base + (size_t)(uint32)c3.x + boff);
        k += 4;
        for (; k + 4 <= e; k += 4) {
            int2 d0 = csr_en[k], d1 = csr_en[k + 1], d2 = csr_en[k + 2], d3 = csr_en[k + 3];
            uint32 w0 = *(const uint32*)(base + (size_t)(uint32)d0.x + boff);
            uint32 w1 = *(const uint32*)(base + (size_t)(uint32)d1.x + boff);
            uint32 w2_ = *(const uint32*)(base + (size_t)(uint32)d2.x + boff);
            uint32 w3 = *(const uint32*)(base + (size_t)(uint32)d3.x + boff);
            AGG_FMA4(c0, v0); AGG_FMA4(c1, v1); AGG_FMA4(c2, v2); AGG_FMA4(c3, v3);
            c0 = d0; c1 = d1; c2 = d2; c3 = d3;
            v0 = w0; v1 = w1; v2 = w2_; v3 = w3;
        }
        AGG_FMA4(c0, v0); AGG_FMA4(c1, v1); AGG_FMA4(c2, v2); AGG_FMA4(c3, v3);
    }
    for (; k < e; k++) {
        int2 c0 = csr_en[k];
        uint32 v0 = *(const uint32*)(base + (size_t)(uint32)c0.x + boff);
        AGG_FMA4(c0, v0);
    }
    float ws_ = dn * dn * 0.0625f;
    float4 b4 = *(const float4*)(bias + (ll << 2));
    a0 = fmaxf(dn * a0 + ws_ * B2F(uself, 0) + b4.x, 0.f);
    a1 = fmaxf(dn * a1 + ws_ * B2F(uself, 1) + b4.y, 0.f);
    a2 = fmaxf(dn * a2 + ws_ * B2F(uself, 2) + b4.z, 0.f);
    a3 = fmaxf(dn * a3 + ws_ * B2F(uself, 3) + b4.w, 0.f);
    if (MODE == 0) {
        uint2 o = make_uint2(pack2bf(a0, a1), pack2bf(a2, a3));
        *(uint2*)((char*)outv + (size_t)n * 256 + (ll << 3)) = o;
    } else {
        uint32 o = q8(a0) | (q8(a1) << 8) | (q8(a2) << 16) | (q8(a3) << 24);
        ((uint32*)outv)[(size_t)n * 32 + ll] = o;
    }
}

// ---------------- layer-3 sweep: gather h2 (int8), pool into per-graph sums ----------
__global__ __launch_bounds__(256) void pool_gather(const uint32* __restrict__ h8,
                                                   const int* __restrict__ row_ptr,
                                                   const int2* __restrict__ csr_en,
                                                   const float* __restrict__ dinv,
                                                   float* __restrict__ pooled,
                                                   const int* __restrict__ batch) {
    int grp = threadIdx.x >> 5;          // 0..7
    int ll  = threadIdx.x & 31;
    int n = blockIdx.x * 8 + grp;        // NN % 8 == 0
    const char* base = (const char*)h8;
    int boff = ll << 2;
    uint32 uself = *(const uint32*)(base + (size_t)n * 128 + boff);
    float dn = dinv[n];
    float a0 = 0.f, a1 = 0.f, a2 = 0.f, a3 = 0.f;
    int s = row_ptr[n], e = row_ptr[n + 1];
    int k = s;
    if (k + 4 <= e) {
        int2 c0 = csr_en[k], c1 = csr_en[k + 1], c2 = csr_en[k + 2], c3 = csr_en[k + 3];
        uint32 v0 = *(const uint32*)(base + (size_t)(uint32)c0.x + boff);
        uint32 v1 = *(const uint32*)(base + (size_t)(uint32)c1.x + boff);
        uint32 v2 = *(const uint32*)(base + (size_t)(uint32)c2.x + boff);
        uint32 v3 = *(const uint32*)(base + (size_t)(uint32)c3.x + boff);
        k += 4;
        for (; k + 4 <= e; k += 4) {
            int2 d0 = csr_en[k], d1 = csr_en[k + 1], d2 = csr_en[k + 2], d3 = csr_en[k + 3];
            uint32 w0 = *(const uint32*)(base + (size_t)(uint32)d0.x + boff);
            uint32 w1 = *(const uint32*)(base + (size_t)(uint32)d1.x + boff);
            uint32 w2_ = *(const uint32*)(base + (size_t)(uint32)d2.x + boff);
            uint32 w3 = *(const uint32*)(base + (size_t)(uint32)d3.x + boff);
            AGG_FMA4(c0, v0); AGG_FMA4(c1, v1); AGG_FMA4(c2, v2); AGG_FMA4(c3, v3);
            c0 = d0; c1 = d1; c2 = d2; c3 = d3;
            v0 = w0; v1 = w1; v2 = w2_; v3 = w3;
        }
        AGG_FMA4(c0, v0); AGG_FMA4(c1, v1); AGG_FMA4(c2, v2); AGG_FMA4(c3, v3);
    }
    for (; k < e; k++) {
        int2 c0 = csr_en[k];
        uint32 v0 = *(const uint32*)(base + (size_t)(uint32)c0.x + boff);
        AGG_FMA4(c0, v0);
    }
    float ws_ = dn * dn * 0.0625f;
    a0 = dn * a0 + ws_ * B2F(uself, 0);
    a1 = dn * a1 + ws_ * B2F(uself, 1);
    a2 = dn * a2 + ws_ * B2F(uself, 2);
    a3 = dn * a3 + ws_ * B2F(uself, 3);
    // fused mean-pool partial: 8 consecutive sorted nodes -> 1-2 graphs typically
    __shared__ float psum[2][128];
    __shared__ int sgmin;
    int g = batch[n];
    if (threadIdx.x == 0) sgmin = g;
    psum[threadIdx.x >> 7][threadIdx.x & 127] = 0.f;
    __syncthreads();
    int slot = g - sgmin;
    if (slot < 2) {
        float* p = &psum[slot][ll << 2];
        atomicAdd(p + 0, a0); atomicAdd(p + 1, a1);
        atomicAdd(p + 2, a2); atomicAdd(p + 3, a3);
    } else {  // pathological tiny-graph case
        float* p = &pooled[g * HH + (ll << 2)];
        atomicAdd(p + 0, a0); atomicAdd(p + 1, a1);
        atomicAdd(p + 2, a2); atomicAdd(p + 3, a3);
    }
    __syncthreads();
    int sl = threadIdx.x >> 7, f = threadIdx.x & 127;
    float v = psum[sl][f];
    int gg = sgmin + sl;
    if (v != 0.f && gg < GG) atomicAdd(&pooled[gg * HH + f], v);
}

// ---------------- final: pm = pooled/c; out = (pm@W3+b3)@Wl+bl ----------------
__global__ __launch_bounds__(128) void final_linear(const float* __restrict__ pooled,
                                                    const int* __restrict__ batch,
                                                    const float* __restrict__ W3,
                                                    const float* __restrict__ b3,
                                                    const float* __restrict__ Wl,
                                                    const float* __restrict__ bl,
                                                    float* __restrict__ out) {
    int g = blockIdx.x;
    int t = threadIdx.x;
    __shared__ float pm[128];
    __shared__ float t1[128];
    __shared__ int cnt_s;
    if (t == 0) {
        int lo = 0, hi = NN;
        while (lo < hi) { int m = (lo + hi) >> 1; if (batch[m] < g) lo = m + 1; else hi = m; }
        int s = lo;
        lo = 0; hi = NN;
        while (lo < hi) { int m = (lo + hi) >> 1; if (batch[m] < g + 1) lo = m + 1; else hi = m; }
        cnt_s = lo - s;
    }
    __syncthreads();
    int cnt = cnt_s;
    pm[t] = (cnt > 0) ? pooled[g * HH + t] / (float)cnt : 0.f;
    __syncthreads();
    float a = (cnt > 0) ? b3[t] : 0.f;
    for (int j = 0; j < 128; j++) a += pm[j] * W3[j * 128 + t];
    t1[t] = a;
    __syncthreads();
    if (t < CC) {
        float o = bl[t];
        for (int j = 0; j < 128; j++) o += t1[j] * Wl[j * CC + t];
        out[g * CC + t] = o;
    }
}

extern "C" void kernel_launch(void* const* d_in, const int* in_sizes, int n_in,
                              void* d_out, int out_size, void* d_ws, size_t ws_size,
                              hipStream_t stream) {
    const float* x    = (const float*)d_in[0];
    const int*   ei   = (const int*)d_in[1];
    const int*   bat  = (const int*)d_in[2];
    const float* W1   = (const float*)d_in[3];
    const float* b1   = (const float*)d_in[4];
    const float* W2   = (const float*)d_in[5];
    const float* b2   = (const float*)d_in[6];
    const float* W3   = (const float*)d_in[7];
    const float* b3   = (const float*)d_in[8];
    const float* Wl   = (const float*)d_in[9];
    const float* bl   = (const float*)d_in[10];
    float* out = (float*)d_out;

    const int* src = ei;
    const int* dst = ei + EE;

    char* ws = (char*)d_ws;
    size_t off = 0;
    auto take = [&](size_t bytes) -> char* {
        char* p = ws + off;
        off += (bytes + 255) & ~(size_t)255;
        return p;
    };
    // deg | pooled contiguous -> one memset clears both
    int*      deg     = (int*)take((size_t)NN * 4);        // 200192 padded
    float*    pooled  = (float*)take((size_t)GG * HH * 4); // 32768
    int*      cursor  = (int*)take((size_t)NN * 4);        // init by scan_add_tw
    float*    dinv    = (float*)take((size_t)NN * 4);
    int*      row_ptr = (int*)take((size_t)(NN + 1) * 4);
    int*      bsum    = (int*)take((size_t)256 * 4);
    int2*     csr_en  = (int2*)take((size_t)EE * 8);
    ushort16* Wt1     = (ushort16*)take((size_t)HH * HH * 2);
    ushort16* Wt2     = (ushort16*)take((size_t)HH * HH * 2);
    uint32*   zA      = (uint32*)take((size_t)NN * HH);    // int8 rows, 128B (6.4MB)
    uint32*   zB      = (uint32*)take((size_t)NN * HH);
    ushort16* bufH    = (ushort16*)take((size_t)NN * HH * 2); // bf16 rows, 256B

    const size_t clr = (((size_t)NN * 4 + 255) & ~(size_t)255) + (size_t)GG * HH * 4;
    hipMemsetAsync(deg, 0, clr, stream);

    count_deg<<<(EE + 255) / 256, 256, 0, stream>>>(dst, deg);
    scan_block<<<NBSCAN, SB, 0, stream>>>(deg, row_ptr, bsum, dinv);
    scan_bsum<<<1, 256, 0, stream>>>(bsum, NBSCAN);
    scan_add_tw<<<NBSCAN + 32, SB, 0, stream>>>(row_ptr, cursor, bsum, W1, W2, Wt1, Wt2);

    // fused: gemm1 (blocks [0,GEMMB)) + CSR fill (blocks [GEMMB, GEMMB+FILLB))
    fill_gemm<<<GEMMB + FILLB, 256, 0, stream>>>(x, Wt1, zA, src, dst, cursor, dinv, csr_en);

    const int aggBlocks = NN / 8;   // 6250 (exact)
    aggregate<0><<<aggBlocks, 256, 0, stream>>>(zA, row_ptr, csr_en, dinv, b1, bufH);  // h1 bf16
    gemm_h<<<GEMMB, 256, 0, stream>>>(bufH, Wt2, zB);                                  // z2 int8
    aggregate<1><<<aggBlocks, 256, 0, stream>>>(zB, row_ptr, csr_en, dinv, b2, zA);    // h2 int8
    pool_gather<<<aggBlocks, 256, 0, stream>>>(zA, row_ptr, csr_en, dinv, pooled, bat);

    final_linear<<<GG, 128, 0, stream>>>(pooled, bat, W3, b3, Wl, bl, out);
}

// Round 18
// 192.239 us; speedup vs baseline: 1.0622x; 1.0622x over previous
//
#include <hip/hip_runtime.h>
#include <hip/hip_bf16.h>

#define NN 50000
#define EE 600000
#define FF 128
#define HH 128
#define CC 10
#define GG 64
#define SB 256
#define NBSCAN ((NN + SB - 1) / SB)   // 196

typedef unsigned int uint32;
typedef unsigned short ushort16;
typedef __attribute__((ext_vector_type(8))) short short8;
typedef __attribute__((ext_vector_type(4))) float f32x4;

__device__ __forceinline__ ushort16 f2bf(float f) {
    __hip_bfloat16 b = __float2bfloat16(f);
    return *reinterpret_cast<ushort16*>(&b);
}
__device__ __forceinline__ uint32 pack2bf(float a, float b) {
    return (uint32)f2bf(a) | ((uint32)f2bf(b) << 16);
}
// int8 quantize with scale 16, clamp +-127
__device__ __forceinline__ int q8(float f) {
    return __float2int_rn(fminf(fmaxf(f * 16.f, -127.f), 127.f)) & 255;
}
// decode byte j (0..3) of u as signed int8 -> float
#define B2F(w, j) ((float)((int)((w) << (24 - 8 * (j))) >> 24))

// ---------------- degree count ----------------
__global__ void count_deg(const int* __restrict__ dst, int* __restrict__ deg) {
    int e = blockIdx.x * blockDim.x + threadIdx.x;
    if (e < EE) atomicAdd(&deg[dst[e]], 1);
}

// ---------------- scan stage 1 (+ dinv fused) ----------------
__global__ __launch_bounds__(SB) void scan_block(const int* __restrict__ deg,
                                                 int* __restrict__ row_ptr,
                                                 int* __restrict__ bsum,
                                                 float* __restrict__ dinv) {
    __shared__ int sm[SB];
    int t = threadIdx.x;
    int i = blockIdx.x * SB + t;
    int v = (i < NN) ? deg[i] : 0;
    if (i < NN) dinv[i] = rsqrtf((float)(v + 1));
    sm[t] = v;
    __syncthreads();
    for (int off = 1; off < SB; off <<= 1) {
        int add = (t >= off) ? sm[t - off] : 0;
        __syncthreads();
        sm[t] += add;
        __syncthreads();
    }
    if (i < NN) row_ptr[i] = sm[t] - v;
    if (t == SB - 1) bsum[blockIdx.x] = sm[t];
}

__global__ void scan_bsum(int* __restrict__ bsum, int nb) {
    __shared__ int sm[256];
    int t = threadIdx.x;
    int v = (t < nb) ? bsum[t] : 0;
    sm[t] = v;
    __syncthreads();
    for (int off = 1; off < 256; off <<= 1) {
        int add = (t >= off) ? sm[t - off] : 0;
        __syncthreads();
        sm[t] += add;
        __syncthreads();
    }
    if (t < nb) bsum[t] = sm[t] - v;
}

// ---------------- scan stage 3 + cursor copy + W transpose (W1,W2 only) ----------------
__global__ __launch_bounds__(SB) void scan_add_tw(int* __restrict__ row_ptr,
                                                  int* __restrict__ cursor,
                                                  const int* __restrict__ bsum,
                                                  const float* __restrict__ W1,
                                                  const float* __restrict__ W2,
                                                  ushort16* __restrict__ T1,
                                                  ushort16* __restrict__ T2) {
    int b = blockIdx.x;
    if (b < NBSCAN) {
        int i = b * SB + threadIdx.x;
        if (i < NN) {
            int v = row_ptr[i] + bsum[b];
            row_ptr[i] = v;
            cursor[i] = v;            // fill_csr bumps this copy directly
        }
        if (i == 0) row_ptr[NN] = EE;
    } else {
        int bi = b - NBSCAN;                 // 0..31
        int wi = bi >> 4;
        const float* W = (wi == 0) ? W1 : W2;
        ushort16* T = (wi == 0) ? T1 : T2;
        int base = (bi & 15) * 256 + threadIdx.x;
#pragma unroll
        for (int i = 0; i < 4; i++) {
            int idx = base + i * 4096;       // 0..16383
            int col = idx & 127;
            int k = idx >> 7;
            T[col * 128 + k] = f2bf(W[k * 128 + col]);
        }
    }
}

// ---------------- CSR fill: (src byte offset into 128B rows, dinv[src]/16) ----------------
__global__ void fill_csr(const int* __restrict__ src, const int* __restrict__ dst,
                         int* __restrict__ cursor,
                         const float* __restrict__ dinv,
                         int2* __restrict__ csr_en) {
    int e = blockIdx.x * blockDim.x + threadIdx.x;
    if (e < EE) {
        int s = src[e], d = dst[e];
        int pos = atomicAdd(&cursor[d], 1);
        csr_en[pos] = make_int2(s * 128, __float_as_int(dinv[s] * 0.0625f));
    }
}

// ---------------- gemm1: fp32 x @ W1 -> int8 z rows (128B) ----------------
__global__ __launch_bounds__(256) void gemm_x(const float* __restrict__ A,
                                              const ushort16* __restrict__ Wt,
                                              uint32* __restrict__ zout) {
    __shared__ char lds[34816];
    int t = threadIdx.x;
    int w = t >> 6, l = t & 63;
    int lrow = l & 15, g = l >> 4;
    int rowBase = blockIdx.x * 64;
    int arow = rowBase + w * 16 + lrow;
    short8 afr[4];
    const char* Ab = (const char*)A;
    bool inb = arow < NN;
#pragma unroll
    for (int s = 0; s < 4; s++) {
        if (inb) {
            float4 f0 = *(const float4*)(Ab + (size_t)arow * 512 + s * 128 + g * 32);
            float4 f1 = *(const float4*)(Ab + (size_t)arow * 512 + s * 128 + g * 32 + 16);
            union { short8 s8; uint32 u[4]; } cv;
            cv.u[0] = pack2bf(f0.x, f0.y);
            cv.u[1] = pack2bf(f0.z, f0.w);
            cv.u[2] = pack2bf(f1.x, f1.y);
            cv.u[3] = pack2bf(f1.z, f1.w);
            afr[s] = cv.s8;
        } else {
            short8 z = {0, 0, 0, 0, 0, 0, 0, 0};
            afr[s] = z;
        }
    }
    const char* Wb = (const char*)Wt;
#pragma unroll
    for (int i = 0; i < 8; i++) {
        int idx = t + i * 256;
        int col = idx >> 4, c16 = idx & 15;
        *(uint4*)(lds + col * 272 + c16 * 16) = *(const uint4*)(Wb + col * 256 + c16 * 16);
    }
    __syncthreads();
    f32x4 acc[8];
#pragma unroll
    for (int c = 0; c < 8; c++) { f32x4 z = {0.f, 0.f, 0.f, 0.f}; acc[c] = z; }
#pragma unroll
    for (int s = 0; s < 4; s++) {
#pragma unroll
        for (int c = 0; c < 8; c++) {
            short8 b = *(const short8*)(lds + (c * 16 + lrow) * 272 + s * 64 + g * 16);
            acc[c] = __builtin_amdgcn_mfma_f32_16x16x32_bf16(afr[s], b, acc[c], 0, 0, 0);
        }
    }
    __syncthreads();
    char* myl = lds + w * 8448;
#pragma unroll
    for (int c = 0; c < 8; c++) {
#pragma unroll
        for (int j = 0; j < 4; j++) {
            *(float*)(myl + (g * 4 + j) * 528 + (c * 16 + lrow) * 4) = acc[c][j];
        }
    }
    __syncthreads();
#pragma unroll
    for (int j = 0; j < 8; j++) {
        int rl = (l >> 5) + 2 * j;
        int ch = l & 31;
        float4 v = *(const float4*)(myl + rl * 528 + ch * 16);
        int grow = rowBase + w * 16 + rl;
        if (grow < NN) {
            uint32 u = q8(v.x) | (q8(v.y) << 8) | (q8(v.z) << 16) | (q8(v.w) << 24);
            zout[(size_t)grow * 32 + ch] = u;
        }
    }
}

// ---------------- gemm: bf16 h rows @ W -> int8 z rows ----------------
__global__ __launch_bounds__(256) void gemm_h(const ushort16* __restrict__ A,
                                              const ushort16* __restrict__ Wt,
                                              uint32* __restrict__ zout) {
    __shared__ char lds[34816];
    int t = threadIdx.x;
    int w = t >> 6, l = t & 63;
    int lrow = l & 15, g = l >> 4;
    int rowBase = blockIdx.x * 64;
    int arow = rowBase + w * 16 + lrow;
    short8 afr[4];
    const char* Ab = (const char*)A;
    bool inb = arow < NN;
#pragma unroll
    for (int s = 0; s < 4; s++) {
        if (inb) {
            afr[s] = *(const short8*)(Ab + (size_t)arow * 256 + s * 64 + g * 16);
        } else {
            short8 z = {0, 0, 0, 0, 0, 0, 0, 0};
            afr[s] = z;
        }
    }
    const char* Wb = (const char*)Wt;
#pragma unroll
    for (int i = 0; i < 8; i++) {
        int idx = t + i * 256;
        int col = idx >> 4, c16 = idx & 15;
        *(uint4*)(lds + col * 272 + c16 * 16) = *(const uint4*)(Wb + col * 256 + c16 * 16);
    }
    __syncthreads();
    f32x4 acc[8];
#pragma unroll
    for (int c = 0; c < 8; c++) { f32x4 z = {0.f, 0.f, 0.f, 0.f}; acc[c] = z; }
#pragma unroll
    for (int s = 0; s < 4; s++) {
#pragma unroll
        for (int c = 0; c < 8; c++) {
            short8 b = *(const short8*)(lds + (c * 16 + lrow) * 272 + s * 64 + g * 16);
            acc[c] = __builtin_amdgcn_mfma_f32_16x16x32_bf16(afr[s], b, acc[c], 0, 0, 0);
        }
    }
    __syncthreads();
    char* myl = lds + w * 8448;
#pragma unroll
    for (int c = 0; c < 8; c++) {
#pragma unroll
        for (int j = 0; j < 4; j++) {
            *(float*)(myl + (g * 4 + j) * 528 + (c * 16 + lrow) * 4) = acc[c][j];
        }
    }
    __syncthreads();
#pragma unroll
    for (int j = 0; j < 8; j++) {
        int rl = (l >> 5) + 2 * j;
        int ch = l & 31;
        float4 v = *(const float4*)(myl + rl * 528 + ch * 16);
        int grow = rowBase + w * 16 + rl;
        if (grow < NN) {
            uint32 u = q8(v.x) | (q8(v.y) << 8) | (q8(v.z) << 16) | (q8(v.w) << 24);
            zout[(size_t)grow * 32 + ch] = u;
        }
    }
}

// decode-accumulate 4 int8 lanes with per-edge weight (dinv[src]/16)
#define AGG_FMA4(c, v)                                             \
    {                                                              \
        float nm = __int_as_float((c).y);                          \
        a0 += nm * B2F(v, 0);                                      \
        a1 += nm * B2F(v, 1);                                      \
        a2 += nm * B2F(v, 2);                                      \
        a3 += nm * B2F(v, 3);                                      \
    }

// ---------------- aggregation: 32-lane group per node, 4-deep pipeline ----------------
// MODE 0: relu -> bf16 row (for gemm_h). MODE 1: relu -> int8 row (h2 for pool_gather).
template <int MODE>
__global__ __launch_bounds__(256) void aggregate(const uint32* __restrict__ z8,
                                                 const int* __restrict__ row_ptr,
                                                 const int2* __restrict__ csr_en,
                                                 const float* __restrict__ dinv,
                                                 const float* __restrict__ bias,
                                                 void* __restrict__ outv) {
    int grp = threadIdx.x >> 5;          // 0..7
    int ll  = threadIdx.x & 31;
    int n = blockIdx.x * 8 + grp;        // NN % 8 == 0
    const char* base = (const char*)z8;
    int boff = ll << 2;
    uint32 uself = *(const uint32*)(base + (size_t)n * 128 + boff);  // issue early
    float dn = dinv[n];
    float a0 = 0.f, a1 = 0.f, a2 = 0.f, a3 = 0.f;
    int s = row_ptr[n], e = row_ptr[n + 1];
    int k = s;
    if (k + 4 <= e) {
        int2 c0 = csr_en[k], c1 = csr_en[k + 1], c2 = csr_en[k + 2], c3 = csr_en[k + 3];
        uint32 v0 = *(const uint32*)(base + (size_t)(uint32)c0.x + boff);
        uint32 v1 = *(const uint32*)(base + (size_t)(uint32)c1.x + boff);
        uint32 v2 = *(const uint32*)(base + (size_t)(uint32)c2.x + boff);
        uint32 v3 = *(const uint32*)(base + (size_t)(uint32)c3.x + boff);
        k += 4;
        for (; k + 4 <= e; k += 4) {
            int2 d0 = csr_en[k], d1 = csr_en[k + 1], d2 = csr_en[k + 2], d3 = csr_en[k + 3];
            uint32 w0 = *(const uint32*)(base + (size_t)(uint32)d0.x + boff);
            uint32 w1 = *(const uint32*)(base + (size_t)(uint32)d1.x + boff);
            uint32 w2_ = *(const uint32*)(base + (size_t)(uint32)d2.x + boff);
            uint32 w3 = *(const uint32*)(base + (size_t)(uint32)d3.x + boff);
            AGG_FMA4(c0, v0); AGG_FMA4(c1, v1); AGG_FMA4(c2, v2); AGG_FMA4(c3, v3);
            c0 = d0; c1 = d1; c2 = d2; c3 = d3;
            v0 = w0; v1 = w1; v2 = w2_; v3 = w3;
        }
        AGG_FMA4(c0, v0); AGG_FMA4(c1, v1); AGG_FMA4(c2, v2); AGG_FMA4(c3, v3);
    }
    for (; k < e; k++) {
        int2 c0 = csr_en[k];
        uint32 v0 = *(const uint32*)(base + (size_t)(uint32)c0.x + boff);
        AGG_FMA4(c0, v0);
    }
    float ws_ = dn * dn * 0.0625f;
    float4 b4 = *(const float4*)(bias + (ll << 2));
    a0 = fmaxf(dn * a0 + ws_ * B2F(uself, 0) + b4.x, 0.f);
    a1 = fmaxf(dn * a1 + ws_ * B2F(uself, 1) + b4.y, 0.f);
    a2 = fmaxf(dn * a2 + ws_ * B2F(uself, 2) + b4.z, 0.f);
    a3 = fmaxf(dn * a3 + ws_ * B2F(uself, 3) + b4.w, 0.f);
    if (MODE == 0) {
        uint2 o = make_uint2(pack2bf(a0, a1), pack2bf(a2, a3));
        *(uint2*)((char*)outv + (size_t)n * 256 + (ll << 3)) = o;
    } else {
        uint32 o = q8(a0) | (q8(a1) << 8) | (q8(a2) << 16) | (q8(a3) << 24);
        ((uint32*)outv)[(size_t)n * 32 + ll] = o;
    }
}

// ---------------- layer-3 sweep: gather h2 (int8), pool into per-graph sums ----------
__global__ __launch_bounds__(256) void pool_gather(const uint32* __restrict__ h8,
                                                   const int* __restrict__ row_ptr,
                                                   const int2* __restrict__ csr_en,
                                                   const float* __restrict__ dinv,
                                                   float* __restrict__ pooled,
                                                   const int* __restrict__ batch) {
    int grp = threadIdx.x >> 5;          // 0..7
    int ll  = threadIdx.x & 31;
    int n = blockIdx.x * 8 + grp;        // NN % 8 == 0
    const char* base = (const char*)h8;
    int boff = ll << 2;
    uint32 uself = *(const uint32*)(base + (size_t)n * 128 + boff);
    float dn = dinv[n];
    float a0 = 0.f, a1 = 0.f, a2 = 0.f, a3 = 0.f;
    int s = row_ptr[n], e = row_ptr[n + 1];
    int k = s;
    if (k + 4 <= e) {
        int2 c0 = csr_en[k], c1 = csr_en[k + 1], c2 = csr_en[k + 2], c3 = csr_en[k + 3];
        uint32 v0 = *(const uint32*)(base + (size_t)(uint32)c0.x + boff);
        uint32 v1 = *(const uint32*)(base + (size_t)(uint32)c1.x + boff);
        uint32 v2 = *(const uint32*)(base + (size_t)(uint32)c2.x + boff);
        uint32 v3 = *(const uint32*)(base + (size_t)(uint32)c3.x + boff);
        k += 4;
        for (; k + 4 <= e; k += 4) {
            int2 d0 = csr_en[k], d1 = csr_en[k + 1], d2 = csr_en[k + 2], d3 = csr_en[k + 3];
            uint32 w0 = *(const uint32*)(base + (size_t)(uint32)d0.x + boff);
            uint32 w1 = *(const uint32*)(base + (size_t)(uint32)d1.x + boff);
            uint32 w2_ = *(const uint32*)(base + (size_t)(uint32)d2.x + boff);
            uint32 w3 = *(const uint32*)(base + (size_t)(uint32)d3.x + boff);
            AGG_FMA4(c0, v0); AGG_FMA4(c1, v1); AGG_FMA4(c2, v2); AGG_FMA4(c3, v3);
            c0 = d0; c1 = d1; c2 = d2; c3 = d3;
            v0 = w0; v1 = w1; v2 = w2_; v3 = w3;
        }
        AGG_FMA4(c0, v0); AGG_FMA4(c1, v1); AGG_FMA4(c2, v2); AGG_FMA4(c3, v3);
    }
    for (; k < e; k++) {
        int2 c0 = csr_en[k];
        uint32 v0 = *(const uint32*)(base + (size_t)(uint32)c0.x + boff);
        AGG_FMA4(c0, v0);
    }
    float ws_ = dn * dn * 0.0625f;
    a0 = dn * a0 + ws_ * B2F(uself, 0);
    a1 = dn * a1 + ws_ * B2F(uself, 1);
    a2 = dn * a2 + ws_ * B2F(uself, 2);
    a3 = dn * a3 + ws_ * B2F(uself, 3);
    // fused mean-pool partial: 8 consecutive sorted nodes -> 1-2 graphs typically
    __shared__ float psum[2][128];
    __shared__ int sgmin;
    int g = batch[n];
    if (threadIdx.x == 0) sgmin = g;
    psum[threadIdx.x >> 7][threadIdx.x & 127] = 0.f;
    __syncthreads();
    int slot = g - sgmin;
    if (slot < 2) {
        float* p = &psum[slot][ll << 2];
        atomicAdd(p + 0, a0); atomicAdd(p + 1, a1);
        atomicAdd(p + 2, a2); atomicAdd(p + 3, a3);
    } else {  // pathological tiny-graph case
        float* p = &pooled[g * HH + (ll << 2)];
        atomicAdd(p + 0, a0); atomicAdd(p + 1, a1);
        atomicAdd(p + 2, a2); atomicAdd(p + 3, a3);
    }
    __syncthreads();
    int sl = threadIdx.x >> 7, f = threadIdx.x & 127;
    float v = psum[sl][f];
    int gg = sgmin + sl;
    if (v != 0.f && gg < GG) atomicAdd(&pooled[gg * HH + f], v);
}

// ---------------- final: pm = pooled/c; out = (pm@W3+b3)@Wl+bl ----------------
__global__ __launch_bounds__(128) void final_linear(const float* __restrict__ pooled,
                                                    const int* __restrict__ batch,
                                                    const float* __restrict__ W3,
                                                    const float* __restrict__ b3,
                                                    const float* __restrict__ Wl,
                                                    const float* __restrict__ bl,
                                                    float* __restrict__ out) {
    int g = blockIdx.x;
    int t = threadIdx.x;
    __shared__ float pm[128];
    __shared__ float t1[128];
    __shared__ int cnt_s;
    if (t == 0) {
        int lo = 0, hi = NN;
        while (lo < hi) { int m = (lo + hi) >> 1; if (batch[m] < g) lo = m + 1; else hi = m; }
        int s = lo;
        lo = 0; hi = NN;
        while (lo < hi) { int m = (lo + hi) >> 1; if (batch[m] < g + 1) lo = m + 1; else hi = m; }
        cnt_s = lo - s;
    }
    __syncthreads();
    int cnt = cnt_s;
    pm[t] = (cnt > 0) ? pooled[g * HH + t] / (float)cnt : 0.f;
    __syncthreads();
    float a = (cnt > 0) ? b3[t] : 0.f;
    for (int j = 0; j < 128; j++) a += pm[j] * W3[j * 128 + t];
    t1[t] = a;
    __syncthreads();
    if (t < CC) {
        float o = bl[t];
        for (int j = 0; j < 128; j++) o += t1[j] * Wl[j * CC + t];
        out[g * CC + t] = o;
    }
}

extern "C" void kernel_launch(void* const* d_in, const int* in_sizes, int n_in,
                              void* d_out, int out_size, void* d_ws, size_t ws_size,
                              hipStream_t stream) {
    const float* x    = (const float*)d_in[0];
    const int*   ei   = (const int*)d_in[1];
    const int*   bat  = (const int*)d_in[2];
    const float* W1   = (const float*)d_in[3];
    const float* b1   = (const float*)d_in[4];
    const float* W2   = (const float*)d_in[5];
    const float* b2   = (const float*)d_in[6];
    const float* W3   = (const float*)d_in[7];
    const float* b3   = (const float*)d_in[8];
    const float* Wl   = (const float*)d_in[9];
    const float* bl   = (const float*)d_in[10];
    float* out = (float*)d_out;

    const int* src = ei;
    const int* dst = ei + EE;

    char* ws = (char*)d_ws;
    size_t off = 0;
    auto take = [&](size_t bytes) -> char* {
        char* p = ws + off;
        off += (bytes + 255) & ~(size_t)255;
        return p;
    };
    // deg | pooled contiguous -> one memset clears both
    int*      deg     = (int*)take((size_t)NN * 4);        // 200192 padded
    float*    pooled  = (float*)take((size_t)GG * HH * 4); // 32768
    int*      cursor  = (int*)take((size_t)NN * 4);        // init by scan_add_tw
    float*    dinv    = (float*)take((size_t)NN * 4);
    int*      row_ptr = (int*)take((size_t)(NN + 1) * 4);
    int*      bsum    = (int*)take((size_t)256 * 4);
    int2*     csr_en  = (int2*)take((size_t)EE * 8);
    ushort16* Wt1     = (ushort16*)take((size_t)HH * HH * 2);
    ushort16* Wt2     = (ushort16*)take((size_t)HH * HH * 2);
    uint32*   zA      = (uint32*)take((size_t)NN * HH);    // int8 rows, 128B (6.4MB)
    uint32*   zB      = (uint32*)take((size_t)NN * HH);
    ushort16* bufH    = (ushort16*)take((size_t)NN * HH * 2); // bf16 rows, 256B

    const size_t clr = (((size_t)NN * 4 + 255) & ~(size_t)255) + (size_t)GG * HH * 4;
    hipMemsetAsync(deg, 0, clr, stream);

    count_deg<<<(EE + 255) / 256, 256, 0, stream>>>(dst, deg);
    scan_block<<<NBSCAN, SB, 0, stream>>>(deg, row_ptr, bsum, dinv);
    scan_bsum<<<1, 256, 0, stream>>>(bsum, NBSCAN);
    scan_add_tw<<<NBSCAN + 32, SB, 0, stream>>>(row_ptr, cursor, bsum, W1, W2, Wt1, Wt2);
    fill_csr<<<(EE + 255) / 256, 256, 0, stream>>>(src, dst, cursor, dinv, csr_en);

    const int gemmBlocks = (NN + 63) / 64;   // 782
    const int aggBlocks  = NN / 8;           // 6250 (exact)
    gemm_x<<<gemmBlocks, 256, 0, stream>>>(x, Wt1, zA);
    aggregate<0><<<aggBlocks, 256, 0, stream>>>(zA, row_ptr, csr_en, dinv, b1, bufH);  // h1 bf16
    gemm_h<<<gemmBlocks, 256, 0, stream>>>(bufH, Wt2, zB);                             // z2 int8
    aggregate<1><<<aggBlocks, 256, 0, stream>>>(zB, row_ptr, csr_en, dinv, b2, zA);    // h2 int8
    pool_gather<<<aggBlocks, 256, 0, stream>>>(zA, row_ptr, csr_en, dinv, pooled, bat);

    final_linear<<<GG, 128, 0, stream>>>(pooled, bat, W3, b3, Wl, bl, out);
}